// Round 5
// baseline (130.146 us; speedup 1.0000x reference)
//
#include <hip/hip_runtime.h>
#include <math.h>

#define F 128
#define HEADS 4
#define DHEAD 32
#define HIST_BLOCKS 1024

typedef unsigned short ushort_t;
typedef __attribute__((ext_vector_type(8))) short short8;   // 8 bf16 (4 VGPR)
typedef __attribute__((ext_vector_type(4))) float f32x4;    // MFMA acc

// round-to-nearest-even fp32 -> bf16
__device__ __forceinline__ ushort_t f2bf(float x) {
  unsigned u = __float_as_uint(x);
  unsigned r = u + 0x7FFFu + ((u >> 16) & 1u);
  return (ushort_t)(r >> 16);
}

// unpack 8 packed bf16 (as int4) -> 8 fp32
__device__ __forceinline__ void unpack8(const int4& r, float* v) {
  int rr[4] = {r.x, r.y, r.z, r.w};
#pragma unroll
  for (int q = 0; q < 4; q++) {
    unsigned u = (unsigned)rr[q];
    v[2 * q] = __uint_as_float(u << 16);
    v[2 * q + 1] = __uint_as_float(u & 0xFFFF0000u);
  }
}

// class of a node: cls = n / 6250 via magic multiply (exact for n < 2.9e6)
#define CLS_MAGIC 687195u
__device__ __forceinline__ int node_cls(int n) {
  return (int)__umulhi((unsigned)n, CLS_MAGIC);
}

// ---------------------------------------------------------------------------
// K-1: pack W (128x128 fp32) into MFMA-fragment-ordered bf16 hi/lo arrays.
// Fragment (kt,nt): lane l, slot j holds W[kt*32 + (l>>4)*8 + j][nt*16+(l&15)].
// hi = truncated top-16 bits; lo = RNE-bf16(w - hi). Residual ~2^-16 rel.
// ---------------------------------------------------------------------------
__global__ __launch_bounds__(256) void wprep_kernel(
    const float* __restrict__ W, ushort_t* __restrict__ whi,
    ushort_t* __restrict__ wlo) {
  int idx = blockIdx.x * 256 + threadIdx.x;  // 0..16383
  if (idx >= 128 * 128) return;
  int j = idx & 7;
  int lane = (idx >> 3) & 63;
  int f = idx >> 9;  // kt*8+nt
  int kt = f >> 3, nt = f & 7;
  int k = kt * 32 + (lane >> 4) * 8 + j;
  int n = nt * 16 + (lane & 15);
  float w = W[k * 128 + n];
  unsigned u = __float_as_uint(w);
  unsigned hb = u & 0xFFFF0000u;
  float lo = w - __uint_as_float(hb);
  whi[idx] = (ushort_t)(hb >> 16);
  wlo[idx] = f2bf(lo);
}

// ---------------------------------------------------------------------------
// K0: zero counts
// ---------------------------------------------------------------------------
__global__ __launch_bounds__(256) void zero_counts_kernel(int* __restrict__ p,
                                                          int N) {
  int i4 = blockIdx.x * 256 + threadIdx.x;
  int base = i4 * 4;
  if (base + 3 < N) {
    *(int4*)&p[base] = make_int4(0, 0, 0, 0);
  } else if (base < N) {
    for (int j = base; j < N; j++) p[j] = 0;
  }
}

// ---------------------------------------------------------------------------
// K1: fused  [0..gemmBlocks): ft = feat @ W via split-precision bf16 MFMA
//            [gemmBlocks..+HIST_BLOCKS): histogram of dst -> counts
// GEMM: block = 64 rows (4 waves x 16), full 128 cols. No LDS.
//   per wave, per kt (K=32 chunk): A-frag from global feat (2xfloat4/lane),
//   trunc-split into hi/lo bf16; 8 nt-tiles x 3 MFMA accumulate fp32.
//   a*b = a_hi*b_hi + a_lo*b_hi + a_hi*b_lo  (residual ~2^-16)
// ---------------------------------------------------------------------------
__global__ __launch_bounds__(256) void gemm_hist_kernel(
    const float* __restrict__ feat, const ushort_t* __restrict__ whi,
    const ushort_t* __restrict__ wlo, ushort_t* __restrict__ ftb, int N,
    const int* __restrict__ dst, int* __restrict__ counts, int E,
    int gemmBlocks) {
  if ((int)blockIdx.x >= gemmBlocks) {
    // ---- histogram path ----
    int hb = blockIdx.x - gemmBlocks;
    for (int i = hb * 256 + (int)threadIdx.x; i < E; i += HIST_BLOCKS * 256)
      atomicAdd(&counts[dst[i]], 1);
    return;
  }
  // ---- MFMA GEMM path ----
  const int t = threadIdx.x;
  const int wv = t >> 6;  // wave 0..3
  const int l = t & 63;
  const int g = l >> 4;   // lane group 0..3
  const int lm = l & 15;
  const int arow = blockIdx.x * 64 + wv * 16 + lm;
  const int arowc = min(arow, N - 1);  // clamp OOB loads (rows independent)

  f32x4 acc[8];
#pragma unroll
  for (int nt = 0; nt < 8; nt++) acc[nt] = (f32x4){0.f, 0.f, 0.f, 0.f};

#pragma unroll
  for (int kt = 0; kt < 4; kt++) {
    const float* ap = feat + (size_t)arowc * F + kt * 32 + g * 8;
    float a[8];
    *(float4*)&a[0] = *(const float4*)ap;
    *(float4*)&a[4] = *(const float4*)(ap + 4);
    short8 ahi, alo;
#pragma unroll
    for (int j = 0; j < 8; j++) {
      unsigned u = __float_as_uint(a[j]);
      unsigned hb = u & 0xFFFF0000u;
      float lo = a[j] - __uint_as_float(hb);
      ahi[j] = (short)(hb >> 16);
      alo[j] = (short)f2bf(lo);
    }
    const ushort_t* bh = whi + (size_t)(kt * 8) * 512 + l * 8;  // frag=512 sh
    const ushort_t* bl = wlo + (size_t)(kt * 8) * 512 + l * 8;
#pragma unroll
    for (int nt = 0; nt < 8; nt++) {
      short8 bhi = *(const short8*)(bh + nt * 512);
      short8 blo = *(const short8*)(bl + nt * 512);
      acc[nt] =
          __builtin_amdgcn_mfma_f32_16x16x32_bf16(ahi, blo, acc[nt], 0, 0, 0);
      acc[nt] =
          __builtin_amdgcn_mfma_f32_16x16x32_bf16(alo, bhi, acc[nt], 0, 0, 0);
      acc[nt] =
          __builtin_amdgcn_mfma_f32_16x16x32_bf16(ahi, bhi, acc[nt], 0, 0, 0);
    }
  }

  // epilogue: C/D layout col = lane&15, row = (lane>>4)*4 + reg (m89-verified)
  const int orow0 = blockIdx.x * 64 + wv * 16 + g * 4;
#pragma unroll
  for (int reg = 0; reg < 4; reg++) {
    int orow = orow0 + reg;
    if (orow < N) {
#pragma unroll
      for (int nt = 0; nt < 8; nt++)
        ftb[(size_t)orow * F + nt * 16 + lm] = f2bf(acc[nt][reg]);
    }
  }
}

// ---------------------------------------------------------------------------
// K3: scan. block-local exclusive + block sums, then per-block bsum prefix add
// ---------------------------------------------------------------------------
__global__ void scan_block_kernel(const int* __restrict__ counts,
                                  int* __restrict__ offs,
                                  int* __restrict__ bsums, int N) {
  __shared__ int s[256];
  int t = threadIdx.x, i = blockIdx.x * 256 + t;
  int v = (i < N) ? counts[i] : 0;
  s[t] = v;
  __syncthreads();
  for (int d = 1; d < 256; d <<= 1) {
    int x = (t >= d) ? s[t - d] : 0;
    __syncthreads();
    s[t] += x;
    __syncthreads();
  }
  if (i < N) offs[i] = s[t] - v;  // block-local exclusive
  if (t == 255) bsums[blockIdx.x] = s[255];
}

__global__ void scan_finish_kernel(int* __restrict__ offs,
                                   const int* __restrict__ bsums, int N) {
  int t = threadIdx.x, b = blockIdx.x;
  int v = (t < b) ? bsums[t] : 0;  // nb <= 256 guaranteed
#pragma unroll
  for (int d = 32; d > 0; d >>= 1) v += __shfl_down(v, d, 64);
  __shared__ int wsum[4];
  if ((t & 63) == 0) wsum[t >> 6] = v;
  __syncthreads();
  int total = wsum[0] + wsum[1] + wsum[2] + wsum[3];
  int i = b * 256 + t;
  if (i < N) offs[i] += total;
}

// ---------------------------------------------------------------------------
// K4: XCD-class-filtered scatter (one XCD owns each dst range -> L2 merge).
// After this kernel offs[n] == end of node n's range; start = end - counts[n].
// ---------------------------------------------------------------------------
#define SCAT_BLOCKS 2048
__global__ __launch_bounds__(256) void scatter8_kernel(
    const int* __restrict__ src, const int* __restrict__ dst,
    int* __restrict__ offs, int* __restrict__ csr, int E) {
  const int cls = blockIdx.x & 7;
  const int bx = blockIdx.x >> 3;       // class-local block index
  const int nbc = SCAT_BLOCKS / 8;      // blocks per class
  const int seg = (E + nbc - 1) / nbc;  // edges per class-block
  const int e0 = bx * seg;
  const int e1 = min(e0 + seg, E);
  for (int e = e0 + (int)threadIdx.x; e < e1; e += 256) {
    int d = dst[e];
    if (node_cls(d) == cls) {
      int pos = atomicAdd(&offs[d], 1);
      csr[pos] = src[e];
    }
  }
}

// ---------------------------------------------------------------------------
// K5: fused per-node online-softmax aggregation, bf16 ft, 4-deep pipelined.
// ---------------------------------------------------------------------------
__global__ __launch_bounds__(256) void aggregate_kernel(
    const ushort_t* __restrict__ ftb, const int* __restrict__ offs_end,
    const int* __restrict__ counts, const int* __restrict__ csr,
    const float* __restrict__ bias, float* __restrict__ out, int N) {
  const int T = blockIdx.x * 256 + threadIdx.x;
  if (T >= N * 16) return;
  const int sub = T & 3;  // quarter of a head's D
  const int p = T >> 2;   // (node, head)
  const int h = p & 3;
  const int n = p >> 2;
  const int dimBase = h * DHEAD + sub * 8;

  const int deg = counts[n];
  const int off = offs_end[n] - deg;

  float ftd[8];
  {
    int4 r = *(const int4*)&ftb[n * F + dimBase];
    unpack8(r, ftd);
  }

  const float LOG2E = 1.4426950408889634f;
  float m = -INFINITY, s = 0.f;
  float acc[8];
#pragma unroll
  for (int j = 0; j < 8; j++) acc[j] = 0.f;

#define PROCESS(RX)                                              \
  do {                                                           \
    float v[8];                                                  \
    unpack8(RX, v);                                              \
    float part = 0.f;                                            \
    _Pragma("unroll") for (int j = 0; j < 8; j++) part =         \
        fmaf(ftd[j], v[j], part);                                \
    part += __shfl_xor(part, 1, 4);                              \
    part += __shfl_xor(part, 2, 4);                              \
    float el = part * LOG2E;                                     \
    float mn = fmaxf(m, el);                                     \
    float scale = exp2f(m - mn);                                 \
    float w = exp2f(el - mn);                                    \
    s = fmaf(s, scale, w);                                       \
    _Pragma("unroll") for (int j = 0; j < 8; j++) acc[j] =       \
        fmaf(acc[j], scale, w * v[j]);                           \
    m = mn;                                                      \
  } while (0)

  int4 R0 = make_int4(0, 0, 0, 0), R1 = R0, R2 = R0, R3 = R0;
  if (deg > 0) {
    int dm1 = deg - 1;
    int s0 = csr[off];
    int s1 = csr[off + min(1, dm1)];
    int s2 = csr[off + min(2, dm1)];
    int s3 = csr[off + min(3, dm1)];
    R0 = *(const int4*)&ftb[s0 * F + dimBase];
    R1 = *(const int4*)&ftb[s1 * F + dimBase];
    R2 = *(const int4*)&ftb[s2 * F + dimBase];
    R3 = *(const int4*)&ftb[s3 * F + dimBase];
  }
  int i = 0;
  for (; i + 4 <= deg; i += 4) {
    int dm1 = deg - 1;
    int sa = csr[off + min(i + 4, dm1)];
    int sb = csr[off + min(i + 5, dm1)];
    int sc = csr[off + min(i + 6, dm1)];
    int sd = csr[off + min(i + 7, dm1)];
    int4 Na = *(const int4*)&ftb[sa * F + dimBase];
    int4 Nb = *(const int4*)&ftb[sb * F + dimBase];
    int4 Nc = *(const int4*)&ftb[sc * F + dimBase];
    int4 Nd = *(const int4*)&ftb[sd * F + dimBase];
    PROCESS(R0);
    PROCESS(R1);
    PROCESS(R2);
    PROCESS(R3);
    R0 = Na; R1 = Nb; R2 = Nc; R3 = Nd;
  }
  int r = deg - i;  // 0..3 remaining, already resident in R0..R2
  if (r > 0) PROCESS(R0);
  if (r > 1) PROCESS(R1);
  if (r > 2) PROCESS(R2);
#undef PROCESS

  float inv = (deg > 0) ? 1.f / s : 0.f;  // deg==0 -> out = bias
#pragma unroll
  for (int j = 0; j < 8; j++)
    out[n * F + dimBase + j] = acc[j] * inv + bias[dimBase + j];
}

// ---------------------------------------------------------------------------
extern "C" void kernel_launch(void* const* d_in, const int* in_sizes, int n_in,
                              void* d_out, int out_size, void* d_ws,
                              size_t ws_size, hipStream_t stream) {
  const float* feat = (const float*)d_in[0];
  const int* src = (const int*)d_in[1];
  const int* dst = (const int*)d_in[2];
  const float* W = (const float*)d_in[3];
  const float* bias = (const float*)d_in[4];
  float* out = (float*)d_out;

  const int N = in_sizes[0] / F;
  const int E = in_sizes[1];

  // workspace layout
  char* ws = (char*)d_ws;
  ushort_t* ftb = (ushort_t*)ws;  // N*128 bf16 = 12.8 MB
  size_t ftB = (size_t)N * F * sizeof(ushort_t);
  ftB = (ftB + 255) & ~(size_t)255;
  int* counts = (int*)(ws + ftB);  // N
  int* offs = counts + N;          // N
  int* bsums = offs + N;           // 256
  int* csr = bsums + 256;          // E
  ushort_t* whi = (ushort_t*)(csr + E);  // 16384 shorts (32 KB)
  ushort_t* wlo = whi + 128 * 128;       // 16384 shorts (32 KB)

  wprep_kernel<<<64, 256, 0, stream>>>(W, whi, wlo);
  zero_counts_kernel<<<(N + 1023) / 1024, 256, 0, stream>>>(counts, N);

  int gemmBlocks = (N + 63) / 64;
  gemm_hist_kernel<<<gemmBlocks + HIST_BLOCKS, 256, 0, stream>>>(
      feat, whi, wlo, ftb, N, dst, counts, E, gemmBlocks);

  int nb = (N + 255) / 256;  // 196 for N=50000 (must be <= 256)
  scan_block_kernel<<<nb, 256, 0, stream>>>(counts, offs, bsums, N);
  scan_finish_kernel<<<nb, 256, 0, stream>>>(offs, bsums, N);

  scatter8_kernel<<<SCAT_BLOCKS, 256, 0, stream>>>(src, dst, offs, csr, E);

  aggregate_kernel<<<(N * 16 + 255) / 256, 256, 0, stream>>>(
      ftb, offs, counts, csr, bias, out, N);
}

// Round 6
// 123.944 us; speedup vs baseline: 1.0500x; 1.0500x over previous
//
#include <hip/hip_runtime.h>
#include <math.h>

#define F 128
#define HEADS 4
#define DHEAD 32
#define HIST_BLOCKS 1024

typedef unsigned short ushort_t;
typedef __attribute__((ext_vector_type(8))) short short8;   // 8 bf16 (4 VGPR)
typedef __attribute__((ext_vector_type(4))) float f32x4;    // MFMA acc

// round-to-nearest-even fp32 -> bf16
__device__ __forceinline__ ushort_t f2bf(float x) {
  unsigned u = __float_as_uint(x);
  unsigned r = u + 0x7FFFu + ((u >> 16) & 1u);
  return (ushort_t)(r >> 16);
}

// unpack 8 packed bf16 (as int4) -> 8 fp32
__device__ __forceinline__ void unpack8(const int4& r, float* v) {
  int rr[4] = {r.x, r.y, r.z, r.w};
#pragma unroll
  for (int q = 0; q < 4; q++) {
    unsigned u = (unsigned)rr[q];
    v[2 * q] = __uint_as_float(u << 16);
    v[2 * q + 1] = __uint_as_float(u & 0xFFFF0000u);
  }
}

// class of a node: cls = n / 6250 via magic multiply (exact for n < 2.9e6)
#define CLS_MAGIC 687195u
__device__ __forceinline__ int node_cls(int n) {
  return (int)__umulhi((unsigned)n, CLS_MAGIC);
}

// ---------------------------------------------------------------------------
// K-1: pack W (128x128 fp32) into MFMA-fragment-ordered bf16 hi/lo arrays.
// ---------------------------------------------------------------------------
__global__ __launch_bounds__(256) void wprep_kernel(
    const float* __restrict__ W, ushort_t* __restrict__ whi,
    ushort_t* __restrict__ wlo) {
  int idx = blockIdx.x * 256 + threadIdx.x;  // 0..16383
  if (idx >= 128 * 128) return;
  int j = idx & 7;
  int lane = (idx >> 3) & 63;
  int f = idx >> 9;  // kt*8+nt
  int kt = f >> 3, nt = f & 7;
  int k = kt * 32 + (lane >> 4) * 8 + j;
  int n = nt * 16 + (lane & 15);
  float w = W[k * 128 + n];
  unsigned u = __float_as_uint(w);
  unsigned hb = u & 0xFFFF0000u;
  float lo = w - __uint_as_float(hb);
  whi[idx] = (ushort_t)(hb >> 16);
  wlo[idx] = f2bf(lo);
}

// ---------------------------------------------------------------------------
// K0: zero the 8 replicated count arrays (8N ints)
// ---------------------------------------------------------------------------
__global__ __launch_bounds__(256) void zero_counts_kernel(int* __restrict__ p,
                                                          int n) {
  int i4 = blockIdx.x * 256 + threadIdx.x;
  int base = i4 * 4;
  if (base + 3 < n) {
    *(int4*)&p[base] = make_int4(0, 0, 0, 0);
  } else if (base < n) {
    for (int j = base; j < n; j++) p[j] = 0;
  }
}

// ---------------------------------------------------------------------------
// K1: fused  [0..gemmBlocks): ft = feat @ W via split-precision bf16 MFMA
//            [gemmBlocks..+HIST_BLOCKS): 8-replica histogram of dst.
// Replica c = e&7 spreads atomic ops over 8x more cache lines (device atomics
// serialize per line at the coherence point: 256 ops/line was ~40us).
// ---------------------------------------------------------------------------
__global__ __launch_bounds__(256) void gemm_hist_kernel(
    const float* __restrict__ feat, const ushort_t* __restrict__ whi,
    const ushort_t* __restrict__ wlo, ushort_t* __restrict__ ftb, int N,
    const int* __restrict__ dst, int* __restrict__ counts8, int E,
    int gemmBlocks) {
  if ((int)blockIdx.x >= gemmBlocks) {
    // ---- histogram path (replicated) ----
    int hb = blockIdx.x - gemmBlocks;
    for (int i = hb * 256 + (int)threadIdx.x; i < E; i += HIST_BLOCKS * 256)
      atomicAdd(&counts8[(i & 7) * N + dst[i]], 1);
    return;
  }
  // ---- MFMA GEMM path ----
  const int t = threadIdx.x;
  const int wv = t >> 6;  // wave 0..3
  const int l = t & 63;
  const int g = l >> 4;   // lane group 0..3
  const int lm = l & 15;
  const int arow = blockIdx.x * 64 + wv * 16 + lm;
  const int arowc = min(arow, N - 1);  // clamp OOB loads (rows independent)

  f32x4 acc[8];
#pragma unroll
  for (int nt = 0; nt < 8; nt++) acc[nt] = (f32x4){0.f, 0.f, 0.f, 0.f};

#pragma unroll
  for (int kt = 0; kt < 4; kt++) {
    const float* ap = feat + (size_t)arowc * F + kt * 32 + g * 8;
    float a[8];
    *(float4*)&a[0] = *(const float4*)ap;
    *(float4*)&a[4] = *(const float4*)(ap + 4);
    short8 ahi, alo;
#pragma unroll
    for (int j = 0; j < 8; j++) {
      unsigned u = __float_as_uint(a[j]);
      unsigned hb = u & 0xFFFF0000u;
      float lo = a[j] - __uint_as_float(hb);
      ahi[j] = (short)(hb >> 16);
      alo[j] = (short)f2bf(lo);
    }
    const ushort_t* bh = whi + (size_t)(kt * 8) * 512 + l * 8;  // frag=512 sh
    const ushort_t* bl = wlo + (size_t)(kt * 8) * 512 + l * 8;
#pragma unroll
    for (int nt = 0; nt < 8; nt++) {
      short8 bhi = *(const short8*)(bh + nt * 512);
      short8 blo = *(const short8*)(bl + nt * 512);
      acc[nt] =
          __builtin_amdgcn_mfma_f32_16x16x32_bf16(ahi, blo, acc[nt], 0, 0, 0);
      acc[nt] =
          __builtin_amdgcn_mfma_f32_16x16x32_bf16(alo, bhi, acc[nt], 0, 0, 0);
      acc[nt] =
          __builtin_amdgcn_mfma_f32_16x16x32_bf16(ahi, bhi, acc[nt], 0, 0, 0);
    }
  }

  // epilogue: C/D layout col = lane&15, row = (lane>>4)*4 + reg (m89-verified)
  const int orow0 = blockIdx.x * 64 + wv * 16 + g * 4;
#pragma unroll
  for (int reg = 0; reg < 4; reg++) {
    int orow = orow0 + reg;
    if (orow < N) {
#pragma unroll
      for (int nt = 0; nt < 8; nt++)
        ftb[(size_t)orow * F + nt * 16 + lm] = f2bf(acc[nt][reg]);
    }
  }
}

// ---------------------------------------------------------------------------
// K3a: scan. sums the 8 replicas -> counts[n] (total, for aggregate) and
// block-local exclusive prefix into offs + per-block sums.
// ---------------------------------------------------------------------------
__global__ void scan_block_kernel(const int* __restrict__ counts8,
                                  int* __restrict__ counts,
                                  int* __restrict__ offs,
                                  int* __restrict__ bsums, int N) {
  __shared__ int s[256];
  int t = threadIdx.x, i = blockIdx.x * 256 + t;
  int v = 0;
  if (i < N) {
#pragma unroll
    for (int c = 0; c < 8; c++) v += counts8[c * N + i];
    counts[i] = v;
  }
  s[t] = v;
  __syncthreads();
  for (int d = 1; d < 256; d <<= 1) {
    int x = (t >= d) ? s[t - d] : 0;
    __syncthreads();
    s[t] += x;
    __syncthreads();
  }
  if (i < N) offs[i] = s[t] - v;  // block-local exclusive
  if (t == 255) bsums[blockIdx.x] = s[255];
}

// K3b: finish offs with block-sum prefix; emit 8 exact sub-range cursors:
// cursor8[c][n] = offs[n] + sum_{c'<c} counts8[c'][n]
__global__ void scan_finish_kernel(int* __restrict__ offs,
                                   const int* __restrict__ bsums,
                                   const int* __restrict__ counts8,
                                   int* __restrict__ cursor8, int N) {
  int t = threadIdx.x, b = blockIdx.x;
  int v = (t < b) ? bsums[t] : 0;  // nb <= 256 guaranteed
#pragma unroll
  for (int d = 32; d > 0; d >>= 1) v += __shfl_down(v, d, 64);
  __shared__ int wsum[4];
  if ((t & 63) == 0) wsum[t >> 6] = v;
  __syncthreads();
  int total = wsum[0] + wsum[1] + wsum[2] + wsum[3];
  int i = b * 256 + t;
  if (i < N) {
    int o = offs[i] + total;
    offs[i] = o;
    int run = o;
#pragma unroll
    for (int c = 0; c < 8; c++) {
      cursor8[c * N + i] = run;
      run += counts8[c * N + i];
    }
  }
}

// ---------------------------------------------------------------------------
// K4: XCD-class-filtered scatter (csr store lines owned by one XCD -> L2
// merge) with 8-way sub-range cursors (8x fewer atomic ops per cursor line).
// offs is NOT modified; it remains the start offset for aggregate.
// ---------------------------------------------------------------------------
#define SCAT_BLOCKS 2048
__global__ __launch_bounds__(256) void scatter8_kernel(
    const int* __restrict__ src, const int* __restrict__ dst,
    int* __restrict__ cursor8, int* __restrict__ csr, int E, int N) {
  const int cls = blockIdx.x & 7;
  const int bx = blockIdx.x >> 3;       // class-local block index
  const int nbc = SCAT_BLOCKS / 8;      // blocks per class
  const int seg = (E + nbc - 1) / nbc;  // edges per class-block
  const int e0 = bx * seg;
  const int e1 = min(e0 + seg, E);
  for (int e = e0 + (int)threadIdx.x; e < e1; e += 256) {
    int d = dst[e];
    if (node_cls(d) == cls) {
      int pos = atomicAdd(&cursor8[(e & 7) * N + d], 1);
      csr[pos] = src[e];
    }
  }
}

// ---------------------------------------------------------------------------
// K5: fused per-node online-softmax aggregation, bf16 ft, 4-deep pipelined.
// ---------------------------------------------------------------------------
__global__ __launch_bounds__(256) void aggregate_kernel(
    const ushort_t* __restrict__ ftb, const int* __restrict__ offs,
    const int* __restrict__ counts, const int* __restrict__ csr,
    const float* __restrict__ bias, float* __restrict__ out, int N) {
  const int T = blockIdx.x * 256 + threadIdx.x;
  if (T >= N * 16) return;
  const int sub = T & 3;  // quarter of a head's D
  const int p = T >> 2;   // (node, head)
  const int h = p & 3;
  const int n = p >> 2;
  const int dimBase = h * DHEAD + sub * 8;

  const int deg = counts[n];
  const int off = offs[n];  // start offset (unmodified by scatter)

  float ftd[8];
  {
    int4 r = *(const int4*)&ftb[n * F + dimBase];
    unpack8(r, ftd);
  }

  const float LOG2E = 1.4426950408889634f;
  float m = -INFINITY, s = 0.f;
  float acc[8];
#pragma unroll
  for (int j = 0; j < 8; j++) acc[j] = 0.f;

#define PROCESS(RX)                                              \
  do {                                                           \
    float v[8];                                                  \
    unpack8(RX, v);                                              \
    float part = 0.f;                                            \
    _Pragma("unroll") for (int j = 0; j < 8; j++) part =         \
        fmaf(ftd[j], v[j], part);                                \
    part += __shfl_xor(part, 1, 4);                              \
    part += __shfl_xor(part, 2, 4);                              \
    float el = part * LOG2E;                                     \
    float mn = fmaxf(m, el);                                     \
    float scale = exp2f(m - mn);                                 \
    float w = exp2f(el - mn);                                    \
    s = fmaf(s, scale, w);                                       \
    _Pragma("unroll") for (int j = 0; j < 8; j++) acc[j] =       \
        fmaf(acc[j], scale, w * v[j]);                           \
    m = mn;                                                      \
  } while (0)

  int4 R0 = make_int4(0, 0, 0, 0), R1 = R0, R2 = R0, R3 = R0;
  if (deg > 0) {
    int dm1 = deg - 1;
    int s0 = csr[off];
    int s1 = csr[off + min(1, dm1)];
    int s2 = csr[off + min(2, dm1)];
    int s3 = csr[off + min(3, dm1)];
    R0 = *(const int4*)&ftb[s0 * F + dimBase];
    R1 = *(const int4*)&ftb[s1 * F + dimBase];
    R2 = *(const int4*)&ftb[s2 * F + dimBase];
    R3 = *(const int4*)&ftb[s3 * F + dimBase];
  }
  int i = 0;
  for (; i + 4 <= deg; i += 4) {
    int dm1 = deg - 1;
    int sa = csr[off + min(i + 4, dm1)];
    int sb = csr[off + min(i + 5, dm1)];
    int sc = csr[off + min(i + 6, dm1)];
    int sd = csr[off + min(i + 7, dm1)];
    int4 Na = *(const int4*)&ftb[sa * F + dimBase];
    int4 Nb = *(const int4*)&ftb[sb * F + dimBase];
    int4 Nc = *(const int4*)&ftb[sc * F + dimBase];
    int4 Nd = *(const int4*)&ftb[sd * F + dimBase];
    PROCESS(R0);
    PROCESS(R1);
    PROCESS(R2);
    PROCESS(R3);
    R0 = Na; R1 = Nb; R2 = Nc; R3 = Nd;
  }
  int r = deg - i;  // 0..3 remaining, already resident in R0..R2
  if (r > 0) PROCESS(R0);
  if (r > 1) PROCESS(R1);
  if (r > 2) PROCESS(R2);
#undef PROCESS

  float inv = (deg > 0) ? 1.f / s : 0.f;  // deg==0 -> out = bias
#pragma unroll
  for (int j = 0; j < 8; j++)
    out[n * F + dimBase + j] = acc[j] * inv + bias[dimBase + j];
}

// ---------------------------------------------------------------------------
extern "C" void kernel_launch(void* const* d_in, const int* in_sizes, int n_in,
                              void* d_out, int out_size, void* d_ws,
                              size_t ws_size, hipStream_t stream) {
  const float* feat = (const float*)d_in[0];
  const int* src = (const int*)d_in[1];
  const int* dst = (const int*)d_in[2];
  const float* W = (const float*)d_in[3];
  const float* bias = (const float*)d_in[4];
  float* out = (float*)d_out;

  const int N = in_sizes[0] / F;
  const int E = in_sizes[1];

  // workspace layout
  char* ws = (char*)d_ws;
  ushort_t* ftb = (ushort_t*)ws;  // N*128 bf16 = 12.8 MB
  size_t ftB = (size_t)N * F * sizeof(ushort_t);
  ftB = (ftB + 255) & ~(size_t)255;
  int* counts = (int*)(ws + ftB);        // N
  int* offs = counts + N;                // N
  int* bsums = offs + N;                 // 256
  int* csr = bsums + 256;                // E
  ushort_t* whi = (ushort_t*)(csr + E);  // 16384 shorts (32 KB)
  ushort_t* wlo = whi + 128 * 128;       // 16384 shorts (32 KB)

  // counts8/cursor8 (8N ints each) live in d_out: they are dead before
  // aggregate_kernel overwrites the full output buffer.
  int* counts8 = (int*)d_out;     // 8N ints = 1.6 MB
  int* cursor8 = counts8 + 8 * N; // 8N ints = 1.6 MB   (<= 25.6 MB total)

  wprep_kernel<<<64, 256, 0, stream>>>(W, whi, wlo);
  zero_counts_kernel<<<(8 * N + 1023) / 1024, 256, 0, stream>>>(counts8,
                                                                8 * N);

  int gemmBlocks = (N + 63) / 64;
  gemm_hist_kernel<<<gemmBlocks + HIST_BLOCKS, 256, 0, stream>>>(
      feat, whi, wlo, ftb, N, dst, counts8, E, gemmBlocks);

  int nb = (N + 255) / 256;  // 196 for N=50000 (must be <= 256)
  scan_block_kernel<<<nb, 256, 0, stream>>>(counts8, counts, offs, bsums, N);
  scan_finish_kernel<<<nb, 256, 0, stream>>>(offs, bsums, counts8, cursor8, N);

  scatter8_kernel<<<SCAT_BLOCKS, 256, 0, stream>>>(src, dst, cursor8, csr, E,
                                                   N);

  aggregate_kernel<<<(N * 16 + 255) / 256, 256, 0, stream>>>(
      ftb, offs, counts, csr, bias, out, N);
}

// Round 7
// 121.734 us; speedup vs baseline: 1.0691x; 1.0182x over previous
//
#include <hip/hip_runtime.h>
#include <math.h>

#define F 128
#define HEADS 4
#define DHEAD 32
#define HIST_H 64          // segments per class; 8*HIST_H hist/scatter blocks
#define CW_MAX 6592        // max nodes per class (LDS cap); N <= 52736

typedef unsigned short ushort_t;
typedef __attribute__((ext_vector_type(8))) short short8;   // 8 bf16 (4 VGPR)
typedef __attribute__((ext_vector_type(4))) float f32x4;    // MFMA acc

// round-to-nearest-even fp32 -> bf16
__device__ __forceinline__ ushort_t f2bf(float x) {
  unsigned u = __float_as_uint(x);
  unsigned r = u + 0x7FFFu + ((u >> 16) & 1u);
  return (ushort_t)(r >> 16);
}

// unpack 8 packed bf16 (as int4) -> 8 fp32
__device__ __forceinline__ void unpack8(const int4& r, float* v) {
  int rr[4] = {r.x, r.y, r.z, r.w};
#pragma unroll
  for (int q = 0; q < 4; q++) {
    unsigned u = (unsigned)rr[q];
    v[2 * q] = __uint_as_float(u << 16);
    v[2 * q + 1] = __uint_as_float(u & 0xFFFF0000u);
  }
}

// ---------------------------------------------------------------------------
// K-1: pack W (128x128 fp32) into MFMA-fragment-ordered bf16 hi/lo arrays.
// ---------------------------------------------------------------------------
__global__ __launch_bounds__(256) void wprep_kernel(
    const float* __restrict__ W, ushort_t* __restrict__ whi,
    ushort_t* __restrict__ wlo) {
  int idx = blockIdx.x * 256 + threadIdx.x;  // 0..16383
  if (idx >= 128 * 128) return;
  int j = idx & 7;
  int lane = (idx >> 3) & 63;
  int f = idx >> 9;  // kt*8+nt
  int kt = f >> 3, nt = f & 7;
  int k = kt * 32 + (lane >> 4) * 8 + j;
  int n = nt * 16 + (lane & 15);
  float w = W[k * 128 + n];
  unsigned u = __float_as_uint(w);
  unsigned hb = u & 0xFFFF0000u;
  float lo = w - __uint_as_float(hb);
  whi[idx] = (ushort_t)(hb >> 16);
  wlo[idx] = f2bf(lo);
}

// ---------------------------------------------------------------------------
// K1: fused  [0..gemmBlocks): ft = feat @ W via split-precision bf16 MFMA
//            [gemmBlocks..+8*HIST_H): LDS partial histograms, NO global
//            atomics. Block (cls=hb&7, h=hb>>3) scans edge segment h and
//            counts dst nodes in its class range into LDS, then dumps the
//            exact partial row to partials[(cls*HIST_H+h)][0..cw).
// ---------------------------------------------------------------------------
__global__ __launch_bounds__(256) void gemm_hist_kernel(
    const float* __restrict__ feat, const ushort_t* __restrict__ whi,
    const ushort_t* __restrict__ wlo, ushort_t* __restrict__ ftb, int N,
    const int* __restrict__ dst, int* __restrict__ partials, int cwp, int E,
    int gemmBlocks) {
  __shared__ int lh[CW_MAX];
  if ((int)blockIdx.x >= gemmBlocks) {
    // ---- partial histogram path ----
    const int hb = blockIdx.x - gemmBlocks;
    const int cls = hb & 7;
    const int h = hb >> 3;
    const unsigned cw = (unsigned)((N + 7) >> 3);
    const int nbase = cls * (int)cw;
    for (int j = threadIdx.x; j < (int)cw; j += 256) lh[j] = 0;
    __syncthreads();
    const int seg = (E + HIST_H - 1) / HIST_H;
    const int e0 = h * seg;
    const int e1 = min(e0 + seg, E);
    for (int e = e0 + (int)threadIdx.x; e < e1; e += 256) {
      int d = dst[e];
      if ((unsigned)d / cw == (unsigned)cls) atomicAdd(&lh[d - nbase], 1);
    }
    __syncthreads();
    int* prow = partials + (size_t)(cls * HIST_H + h) * cwp;
    for (int j = threadIdx.x; j < (int)cw; j += 256) prow[j] = lh[j];
    return;
  }
  // ---- MFMA GEMM path ----
  const int t = threadIdx.x;
  const int wv = t >> 6;  // wave 0..3
  const int l = t & 63;
  const int g = l >> 4;   // lane group 0..3
  const int lm = l & 15;
  const int arow = blockIdx.x * 64 + wv * 16 + lm;
  const int arowc = min(arow, N - 1);  // clamp OOB loads (rows independent)

  f32x4 acc[8];
#pragma unroll
  for (int nt = 0; nt < 8; nt++) acc[nt] = (f32x4){0.f, 0.f, 0.f, 0.f};

#pragma unroll
  for (int kt = 0; kt < 4; kt++) {
    const float* ap = feat + (size_t)arowc * F + kt * 32 + g * 8;
    float a[8];
    *(float4*)&a[0] = *(const float4*)ap;
    *(float4*)&a[4] = *(const float4*)(ap + 4);
    short8 ahi, alo;
#pragma unroll
    for (int j = 0; j < 8; j++) {
      unsigned u = __float_as_uint(a[j]);
      unsigned hb2 = u & 0xFFFF0000u;
      float lo = a[j] - __uint_as_float(hb2);
      ahi[j] = (short)(hb2 >> 16);
      alo[j] = (short)f2bf(lo);
    }
    const ushort_t* bh = whi + (size_t)(kt * 8) * 512 + l * 8;  // frag=512 sh
    const ushort_t* bl = wlo + (size_t)(kt * 8) * 512 + l * 8;
#pragma unroll
    for (int nt = 0; nt < 8; nt++) {
      short8 bhi = *(const short8*)(bh + nt * 512);
      short8 blo = *(const short8*)(bl + nt * 512);
      acc[nt] =
          __builtin_amdgcn_mfma_f32_16x16x32_bf16(ahi, blo, acc[nt], 0, 0, 0);
      acc[nt] =
          __builtin_amdgcn_mfma_f32_16x16x32_bf16(alo, bhi, acc[nt], 0, 0, 0);
      acc[nt] =
          __builtin_amdgcn_mfma_f32_16x16x32_bf16(ahi, bhi, acc[nt], 0, 0, 0);
    }
  }

  // epilogue: C/D layout col = lane&15, row = (lane>>4)*4 + reg (m89-verified)
  const int orow0 = blockIdx.x * 64 + wv * 16 + g * 4;
#pragma unroll
  for (int reg = 0; reg < 4; reg++) {
    int orow = orow0 + reg;
    if (orow < N) {
#pragma unroll
      for (int nt = 0; nt < 8; nt++)
        ftb[(size_t)orow * F + nt * 16 + lm] = f2bf(acc[nt][reg]);
    }
  }
}

// ---------------------------------------------------------------------------
// K3a: counts[n] = sum_h partials[cls(n)][h][j(n)]; block-local exclusive
// prefix into offs + per-block sums. All reads coalesced (64 slices).
// ---------------------------------------------------------------------------
__global__ void scan_block_kernel(const int* __restrict__ partials, int cwp,
                                  int* __restrict__ counts,
                                  int* __restrict__ offs,
                                  int* __restrict__ bsums, int N) {
  __shared__ int s[256];
  int t = threadIdx.x, i = blockIdx.x * 256 + t;
  int v = 0;
  if (i < N) {
    unsigned cw = (unsigned)((N + 7) >> 3);
    int c = (int)((unsigned)i / cw);
    int j = i - c * (int)cw;
    const int* base = partials + (size_t)c * HIST_H * cwp + j;
#pragma unroll 8
    for (int h = 0; h < HIST_H; h++) v += base[(size_t)h * cwp];
    counts[i] = v;
  }
  s[t] = v;
  __syncthreads();
  for (int d = 1; d < 256; d <<= 1) {
    int x = (t >= d) ? s[t - d] : 0;
    __syncthreads();
    s[t] += x;
    __syncthreads();
  }
  if (i < N) offs[i] = s[t] - v;  // block-local exclusive
  if (t == 255) bsums[blockIdx.x] = s[255];
}

// K3b: finish offs with block-sum prefix; emit exact per-(class,segment)
// cursors: cursors[c][h][j] = offs[n] + sum_{h'<h} partials[c][h'][j]
__global__ void scan_finish_kernel(int* __restrict__ offs,
                                   const int* __restrict__ bsums,
                                   const int* __restrict__ partials,
                                   int* __restrict__ cursors, int cwp, int N) {
  int t = threadIdx.x, b = blockIdx.x;
  int v = (t < b) ? bsums[t] : 0;  // nb <= 256 guaranteed
#pragma unroll
  for (int d = 32; d > 0; d >>= 1) v += __shfl_down(v, d, 64);
  __shared__ int wsum[4];
  if ((t & 63) == 0) wsum[t >> 6] = v;
  __syncthreads();
  int total = wsum[0] + wsum[1] + wsum[2] + wsum[3];
  int i = b * 256 + t;
  if (i < N) {
    int o = offs[i] + total;
    offs[i] = o;
    unsigned cw = (unsigned)((N + 7) >> 3);
    int c = (int)((unsigned)i / cw);
    int j = i - c * (int)cw;
    const int* pb = partials + (size_t)c * HIST_H * cwp + j;
    int* cb = cursors + (size_t)c * HIST_H * cwp + j;
    int run = o;
#pragma unroll 8
    for (int h = 0; h < HIST_H; h++) {
      cb[(size_t)h * cwp] = run;
      run += pb[(size_t)h * cwp];
    }
  }
}

// ---------------------------------------------------------------------------
// K4: scatter with ZERO global atomics. Block (cls,h) loads its exact cursor
// row into LDS, rescans segment h, LDS-atomicAdd gives the csr slot. csr
// lines of a class stay owned by one XCD (bid&7) -> stores merge in L2.
// offs is NOT modified; it remains the start offset for aggregate.
// ---------------------------------------------------------------------------
__global__ __launch_bounds__(256) void scatter_kernel(
    const int* __restrict__ src, const int* __restrict__ dst,
    const int* __restrict__ cursors, int cwp, int* __restrict__ csr, int E,
    int N) {
  __shared__ int lcur[CW_MAX];
  const int cls = blockIdx.x & 7;
  const int h = blockIdx.x >> 3;
  const unsigned cw = (unsigned)((N + 7) >> 3);
  const int nbase = cls * (int)cw;
  const int* crow = cursors + (size_t)(cls * HIST_H + h) * cwp;
  for (int j = threadIdx.x; j < (int)cw; j += 256) lcur[j] = crow[j];
  __syncthreads();
  const int seg = (E + HIST_H - 1) / HIST_H;
  const int e0 = h * seg;
  const int e1 = min(e0 + seg, E);
  for (int e = e0 + (int)threadIdx.x; e < e1; e += 256) {
    int d = dst[e];
    int sv = src[e];  // unconditional coalesced read
    if ((unsigned)d / cw == (unsigned)cls) {
      int pos = atomicAdd(&lcur[d - nbase], 1);
      csr[pos] = sv;
    }
  }
}

// ---------------------------------------------------------------------------
// K5: fused per-node online-softmax aggregation, bf16 ft, 4-deep pipelined.
// ---------------------------------------------------------------------------
__global__ __launch_bounds__(256) void aggregate_kernel(
    const ushort_t* __restrict__ ftb, const int* __restrict__ offs,
    const int* __restrict__ counts, const int* __restrict__ csr,
    const float* __restrict__ bias, float* __restrict__ out, int N) {
  const int T = blockIdx.x * 256 + threadIdx.x;
  if (T >= N * 16) return;
  const int sub = T & 3;  // quarter of a head's D
  const int p = T >> 2;   // (node, head)
  const int h = p & 3;
  const int n = p >> 2;
  const int dimBase = h * DHEAD + sub * 8;

  const int deg = counts[n];
  const int off = offs[n];  // start offset (unmodified by scatter)

  float ftd[8];
  {
    int4 r = *(const int4*)&ftb[n * F + dimBase];
    unpack8(r, ftd);
  }

  const float LOG2E = 1.4426950408889634f;
  float m = -INFINITY, s = 0.f;
  float acc[8];
#pragma unroll
  for (int j = 0; j < 8; j++) acc[j] = 0.f;

#define PROCESS(RX)                                              \
  do {                                                           \
    float v[8];                                                  \
    unpack8(RX, v);                                              \
    float part = 0.f;                                            \
    _Pragma("unroll") for (int j = 0; j < 8; j++) part =         \
        fmaf(ftd[j], v[j], part);                                \
    part += __shfl_xor(part, 1, 4);                              \
    part += __shfl_xor(part, 2, 4);                              \
    float el = part * LOG2E;                                     \
    float mn = fmaxf(m, el);                                     \
    float scale = exp2f(m - mn);                                 \
    float w = exp2f(el - mn);                                    \
    s = fmaf(s, scale, w);                                       \
    _Pragma("unroll") for (int j = 0; j < 8; j++) acc[j] =       \
        fmaf(acc[j], scale, w * v[j]);                           \
    m = mn;                                                      \
  } while (0)

  int4 R0 = make_int4(0, 0, 0, 0), R1 = R0, R2 = R0, R3 = R0;
  if (deg > 0) {
    int dm1 = deg - 1;
    int s0 = csr[off];
    int s1 = csr[off + min(1, dm1)];
    int s2 = csr[off + min(2, dm1)];
    int s3 = csr[off + min(3, dm1)];
    R0 = *(const int4*)&ftb[s0 * F + dimBase];
    R1 = *(const int4*)&ftb[s1 * F + dimBase];
    R2 = *(const int4*)&ftb[s2 * F + dimBase];
    R3 = *(const int4*)&ftb[s3 * F + dimBase];
  }
  int i = 0;
  for (; i + 4 <= deg; i += 4) {
    int dm1 = deg - 1;
    int sa = csr[off + min(i + 4, dm1)];
    int sb = csr[off + min(i + 5, dm1)];
    int sc = csr[off + min(i + 6, dm1)];
    int sd = csr[off + min(i + 7, dm1)];
    int4 Na = *(const int4*)&ftb[sa * F + dimBase];
    int4 Nb = *(const int4*)&ftb[sb * F + dimBase];
    int4 Nc = *(const int4*)&ftb[sc * F + dimBase];
    int4 Nd = *(const int4*)&ftb[sd * F + dimBase];
    PROCESS(R0);
    PROCESS(R1);
    PROCESS(R2);
    PROCESS(R3);
    R0 = Na; R1 = Nb; R2 = Nc; R3 = Nd;
  }
  int r = deg - i;  // 0..3 remaining, already resident in R0..R2
  if (r > 0) PROCESS(R0);
  if (r > 1) PROCESS(R1);
  if (r > 2) PROCESS(R2);
#undef PROCESS

  float inv = (deg > 0) ? 1.f / s : 0.f;  // deg==0 -> out = bias
#pragma unroll
  for (int j = 0; j < 8; j++)
    out[n * F + dimBase + j] = acc[j] * inv + bias[dimBase + j];
}

// ---------------------------------------------------------------------------
extern "C" void kernel_launch(void* const* d_in, const int* in_sizes, int n_in,
                              void* d_out, int out_size, void* d_ws,
                              size_t ws_size, hipStream_t stream) {
  const float* feat = (const float*)d_in[0];
  const int* src = (const int*)d_in[1];
  const int* dst = (const int*)d_in[2];
  const float* W = (const float*)d_in[3];
  const float* bias = (const float*)d_in[4];
  float* out = (float*)d_out;

  const int N = in_sizes[0] / F;
  const int E = in_sizes[1];
  const int cw = (N + 7) >> 3;          // nodes per class (<= CW_MAX)
  const int cwp = (cw + 15) & ~15;      // padded row (64B aligned)

  // workspace layout (ws is large; ~42 MB used)
  char* ws = (char*)d_ws;
  ushort_t* ftb = (ushort_t*)ws;  // N*128 bf16 = 12.8 MB
  size_t ftB = (size_t)N * F * sizeof(ushort_t);
  ftB = (ftB + 255) & ~(size_t)255;
  int* counts = (int*)(ws + ftB);              // N
  int* offs = counts + N;                      // N
  int* bsums = offs + N;                       // 256
  int* csr = bsums + 256;                      // E
  ushort_t* whi = (ushort_t*)(csr + E);        // 16384 shorts (32 KB)
  ushort_t* wlo = whi + 128 * 128;             // 16384 shorts (32 KB)
  int* partials = (int*)(wlo + 128 * 128);     // 8*HIST_H*cwp ints (12.8 MB)
  int* cursors = partials + 8 * HIST_H * cwp;  // 8*HIST_H*cwp ints (12.8 MB)

  wprep_kernel<<<64, 256, 0, stream>>>(W, whi, wlo);

  int gemmBlocks = (N + 63) / 64;
  gemm_hist_kernel<<<gemmBlocks + 8 * HIST_H, 256, 0, stream>>>(
      feat, whi, wlo, ftb, N, dst, partials, cwp, E, gemmBlocks);

  int nb = (N + 255) / 256;  // 196 for N=50000 (must be <= 256)
  scan_block_kernel<<<nb, 256, 0, stream>>>(partials, cwp, counts, offs,
                                            bsums, N);
  scan_finish_kernel<<<nb, 256, 0, stream>>>(offs, bsums, partials, cursors,
                                             cwp, N);

  scatter_kernel<<<8 * HIST_H, 256, 0, stream>>>(src, dst, cursors, cwp, csr,
                                                 E, N);

  aggregate_kernel<<<(N * 16 + 255) / 256, 256, 0, stream>>>(
      ftb, offs, counts, csr, bias, out, N);
}

// Round 8
// 105.545 us; speedup vs baseline: 1.2331x; 1.1534x over previous
//
#include <hip/hip_runtime.h>
#include <math.h>

#define F 128
#define HEADS 4
#define DHEAD 32
#define HIST_H 128         // segments per class; 8*HIST_H hist/scatter blocks
#define CW_MAX 6592        // max nodes per class (LDS cap); N <= 52736

typedef unsigned short ushort_t;
typedef __attribute__((ext_vector_type(8))) short short8;   // 8 bf16 (4 VGPR)
typedef __attribute__((ext_vector_type(4))) float f32x4;    // MFMA acc

// round-to-nearest-even fp32 -> bf16
__device__ __forceinline__ ushort_t f2bf(float x) {
  unsigned u = __float_as_uint(x);
  unsigned r = u + 0x7FFFu + ((u >> 16) & 1u);
  return (ushort_t)(r >> 16);
}

// unpack 8 packed bf16 (as int4) -> 8 fp32
__device__ __forceinline__ void unpack8(const int4& r, float* v) {
  int rr[4] = {r.x, r.y, r.z, r.w};
#pragma unroll
  for (int q = 0; q < 4; q++) {
    unsigned u = (unsigned)rr[q];
    v[2 * q] = __uint_as_float(u << 16);
    v[2 * q + 1] = __uint_as_float(u & 0xFFFF0000u);
  }
}

// ---------------------------------------------------------------------------
// K-1: pack W (128x128 fp32) into MFMA-fragment-ordered bf16 hi/lo arrays.
// ---------------------------------------------------------------------------
__global__ __launch_bounds__(256) void wprep_kernel(
    const float* __restrict__ W, ushort_t* __restrict__ whi,
    ushort_t* __restrict__ wlo) {
  int idx = blockIdx.x * 256 + threadIdx.x;  // 0..16383
  if (idx >= 128 * 128) return;
  int j = idx & 7;
  int lane = (idx >> 3) & 63;
  int f = idx >> 9;  // kt*8+nt
  int kt = f >> 3, nt = f & 7;
  int k = kt * 32 + (lane >> 4) * 8 + j;
  int n = nt * 16 + (lane & 15);
  float w = W[k * 128 + n];
  unsigned u = __float_as_uint(w);
  unsigned hb = u & 0xFFFF0000u;
  float lo = w - __uint_as_float(hb);
  whi[idx] = (ushort_t)(hb >> 16);
  wlo[idx] = f2bf(lo);
}

// ---------------------------------------------------------------------------
// K1: ft = feat @ W via split-precision bf16 MFMA. Standalone (no LDS).
// ---------------------------------------------------------------------------
__global__ __launch_bounds__(256) void gemm_kernel(
    const float* __restrict__ feat, const ushort_t* __restrict__ whi,
    const ushort_t* __restrict__ wlo, ushort_t* __restrict__ ftb, int N) {
  const int t = threadIdx.x;
  const int wv = t >> 6;  // wave 0..3
  const int l = t & 63;
  const int g = l >> 4;   // lane group 0..3
  const int lm = l & 15;
  const int arow = blockIdx.x * 64 + wv * 16 + lm;
  const int arowc = min(arow, N - 1);  // clamp OOB loads (rows independent)

  f32x4 acc[8];
#pragma unroll
  for (int nt = 0; nt < 8; nt++) acc[nt] = (f32x4){0.f, 0.f, 0.f, 0.f};

#pragma unroll
  for (int kt = 0; kt < 4; kt++) {
    const float* ap = feat + (size_t)arowc * F + kt * 32 + g * 8;
    float a[8];
    *(float4*)&a[0] = *(const float4*)ap;
    *(float4*)&a[4] = *(const float4*)(ap + 4);
    short8 ahi, alo;
#pragma unroll
    for (int j = 0; j < 8; j++) {
      unsigned u = __float_as_uint(a[j]);
      unsigned hb2 = u & 0xFFFF0000u;
      float lo = a[j] - __uint_as_float(hb2);
      ahi[j] = (short)(hb2 >> 16);
      alo[j] = (short)f2bf(lo);
    }
    const ushort_t* bh = whi + (size_t)(kt * 8) * 512 + l * 8;  // frag=512 sh
    const ushort_t* bl = wlo + (size_t)(kt * 8) * 512 + l * 8;
#pragma unroll
    for (int nt = 0; nt < 8; nt++) {
      short8 bhi = *(const short8*)(bh + nt * 512);
      short8 blo = *(const short8*)(bl + nt * 512);
      acc[nt] =
          __builtin_amdgcn_mfma_f32_16x16x32_bf16(ahi, blo, acc[nt], 0, 0, 0);
      acc[nt] =
          __builtin_amdgcn_mfma_f32_16x16x32_bf16(alo, bhi, acc[nt], 0, 0, 0);
      acc[nt] =
          __builtin_amdgcn_mfma_f32_16x16x32_bf16(ahi, bhi, acc[nt], 0, 0, 0);
    }
  }

  // epilogue: C/D layout col = lane&15, row = (lane>>4)*4 + reg (m89-verified)
  const int orow0 = blockIdx.x * 64 + wv * 16 + g * 4;
#pragma unroll
  for (int reg = 0; reg < 4; reg++) {
    int orow = orow0 + reg;
    if (orow < N) {
#pragma unroll
      for (int nt = 0; nt < 8; nt++)
        ftb[(size_t)orow * F + nt * 16 + lm] = f2bf(acc[nt][reg]);
    }
  }
}

// ---------------------------------------------------------------------------
// K2: LDS partial histograms, no global atomics. Block (cls=bid&7, h=bid>>3)
// scans edge segment h, counts dst in its class range (range compare, no
// division), dumps exact partial row. 4-deep batched edge loop.
// ---------------------------------------------------------------------------
__global__ __launch_bounds__(256) void hist_kernel(
    const int* __restrict__ dst, int* __restrict__ partials, int cwp, int E,
    int N) {
  __shared__ int lh[CW_MAX];
  const int cls = blockIdx.x & 7;
  const int h = blockIdx.x >> 3;
  const int cw = (N + 7) >> 3;
  const int nbase = cls * cw;
  for (int j = threadIdx.x; j < cw; j += 256) lh[j] = 0;
  __syncthreads();
  const int seg = (E + HIST_H - 1) / HIST_H;
  const int e0 = h * seg;
  const int e1 = min(e0 + seg, E);
  int e = e0 + (int)threadIdx.x;
  for (; e + 768 < e1; e += 1024) {
    int d0 = dst[e];
    int d1 = dst[e + 256];
    int d2 = dst[e + 512];
    int d3 = dst[e + 768];
    if ((unsigned)(d0 - nbase) < (unsigned)cw) atomicAdd(&lh[d0 - nbase], 1);
    if ((unsigned)(d1 - nbase) < (unsigned)cw) atomicAdd(&lh[d1 - nbase], 1);
    if ((unsigned)(d2 - nbase) < (unsigned)cw) atomicAdd(&lh[d2 - nbase], 1);
    if ((unsigned)(d3 - nbase) < (unsigned)cw) atomicAdd(&lh[d3 - nbase], 1);
  }
  for (; e < e1; e += 256) {
    int d = dst[e];
    if ((unsigned)(d - nbase) < (unsigned)cw) atomicAdd(&lh[d - nbase], 1);
  }
  __syncthreads();
  int* prow = partials + (size_t)(cls * HIST_H + h) * cwp;
  for (int j = threadIdx.x; j < cw; j += 256) prow[j] = lh[j];
}

// ---------------------------------------------------------------------------
// K3a: counts[n] = sum_h partials[cls(n)][h][j(n)]; block-local exclusive
// prefix into offs + per-block sums.
// ---------------------------------------------------------------------------
__global__ void scan_block_kernel(const int* __restrict__ partials, int cwp,
                                  int* __restrict__ counts,
                                  int* __restrict__ offs,
                                  int* __restrict__ bsums, int N) {
  __shared__ int s[256];
  int t = threadIdx.x, i = blockIdx.x * 256 + t;
  int v = 0;
  if (i < N) {
    int cw = (N + 7) >> 3;
    int c = i / cw;
    int j = i - c * cw;
    const int* base = partials + (size_t)c * HIST_H * cwp + j;
#pragma unroll 8
    for (int h = 0; h < HIST_H; h++) v += base[(size_t)h * cwp];
    counts[i] = v;
  }
  s[t] = v;
  __syncthreads();
  for (int d = 1; d < 256; d <<= 1) {
    int x = (t >= d) ? s[t - d] : 0;
    __syncthreads();
    s[t] += x;
    __syncthreads();
  }
  if (i < N) offs[i] = s[t] - v;  // block-local exclusive
  if (t == 255) bsums[blockIdx.x] = s[255];
}

// K3b: finish offs with block-sum prefix; emit exact per-(class,segment)
// cursors: cursors[c][h][j] = offs[n] + sum_{h'<h} partials[c][h'][j]
__global__ void scan_finish_kernel(int* __restrict__ offs,
                                   const int* __restrict__ bsums,
                                   const int* __restrict__ partials,
                                   int* __restrict__ cursors, int cwp, int N) {
  int t = threadIdx.x, b = blockIdx.x;
  int v = (t < b) ? bsums[t] : 0;  // nb <= 256 guaranteed
#pragma unroll
  for (int d = 32; d > 0; d >>= 1) v += __shfl_down(v, d, 64);
  __shared__ int wsum[4];
  if ((t & 63) == 0) wsum[t >> 6] = v;
  __syncthreads();
  int total = wsum[0] + wsum[1] + wsum[2] + wsum[3];
  int i = b * 256 + t;
  if (i < N) {
    int o = offs[i] + total;
    offs[i] = o;
    int cw = (N + 7) >> 3;
    int c = i / cw;
    int j = i - c * cw;
    const int* pb = partials + (size_t)c * HIST_H * cwp + j;
    int* cb = cursors + (size_t)c * HIST_H * cwp + j;
    int run = o;
#pragma unroll 8
    for (int h = 0; h < HIST_H; h++) {
      cb[(size_t)h * cwp] = run;
      run += pb[(size_t)h * cwp];
    }
  }
}

// ---------------------------------------------------------------------------
// K4: scatter, zero global atomics. Block (cls,h) loads its exact cursor row
// into LDS, rescans segment h (4-deep batched), LDS-atomicAdd -> csr slot.
// csr lines of a class owned by one XCD (bid&7) -> stores merge in L2.
// ---------------------------------------------------------------------------
__global__ __launch_bounds__(256) void scatter_kernel(
    const int* __restrict__ src, const int* __restrict__ dst,
    const int* __restrict__ cursors, int cwp, int* __restrict__ csr, int E,
    int N) {
  __shared__ int lcur[CW_MAX];
  const int cls = blockIdx.x & 7;
  const int h = blockIdx.x >> 3;
  const int cw = (N + 7) >> 3;
  const int nbase = cls * cw;
  const int* crow = cursors + (size_t)(cls * HIST_H + h) * cwp;
  for (int j = threadIdx.x; j < cw; j += 256) lcur[j] = crow[j];
  __syncthreads();
  const int seg = (E + HIST_H - 1) / HIST_H;
  const int e0 = h * seg;
  const int e1 = min(e0 + seg, E);
  int e = e0 + (int)threadIdx.x;
  for (; e + 768 < e1; e += 1024) {
    int d0 = dst[e];
    int d1 = dst[e + 256];
    int d2 = dst[e + 512];
    int d3 = dst[e + 768];
    int s0 = src[e];
    int s1 = src[e + 256];
    int s2 = src[e + 512];
    int s3 = src[e + 768];
    if ((unsigned)(d0 - nbase) < (unsigned)cw)
      csr[atomicAdd(&lcur[d0 - nbase], 1)] = s0;
    if ((unsigned)(d1 - nbase) < (unsigned)cw)
      csr[atomicAdd(&lcur[d1 - nbase], 1)] = s1;
    if ((unsigned)(d2 - nbase) < (unsigned)cw)
      csr[atomicAdd(&lcur[d2 - nbase], 1)] = s2;
    if ((unsigned)(d3 - nbase) < (unsigned)cw)
      csr[atomicAdd(&lcur[d3 - nbase], 1)] = s3;
  }
  for (; e < e1; e += 256) {
    int d = dst[e];
    int sv = src[e];
    if ((unsigned)(d - nbase) < (unsigned)cw)
      csr[atomicAdd(&lcur[d - nbase], 1)] = sv;
  }
}

// ---------------------------------------------------------------------------
// K5: fused per-node online-softmax aggregation, bf16 ft, 4-deep pipelined.
// ---------------------------------------------------------------------------
__global__ __launch_bounds__(256) void aggregate_kernel(
    const ushort_t* __restrict__ ftb, const int* __restrict__ offs,
    const int* __restrict__ counts, const int* __restrict__ csr,
    const float* __restrict__ bias, float* __restrict__ out, int N) {
  const int T = blockIdx.x * 256 + threadIdx.x;
  if (T >= N * 16) return;
  const int sub = T & 3;  // quarter of a head's D
  const int p = T >> 2;   // (node, head)
  const int h = p & 3;
  const int n = p >> 2;
  const int dimBase = h * DHEAD + sub * 8;

  const int deg = counts[n];
  const int off = offs[n];  // start offset (unmodified by scatter)

  float ftd[8];
  {
    int4 r = *(const int4*)&ftb[n * F + dimBase];
    unpack8(r, ftd);
  }

  const float LOG2E = 1.4426950408889634f;
  float m = -INFINITY, s = 0.f;
  float acc[8];
#pragma unroll
  for (int j = 0; j < 8; j++) acc[j] = 0.f;

#define PROCESS(RX)                                              \
  do {                                                           \
    float v[8];                                                  \
    unpack8(RX, v);                                              \
    float part = 0.f;                                            \
    _Pragma("unroll") for (int j = 0; j < 8; j++) part =         \
        fmaf(ftd[j], v[j], part);                                \
    part += __shfl_xor(part, 1, 4);                              \
    part += __shfl_xor(part, 2, 4);                              \
    float el = part * LOG2E;                                     \
    float mn = fmaxf(m, el);                                     \
    float scale = exp2f(m - mn);                                 \
    float w = exp2f(el - mn);                                    \
    s = fmaf(s, scale, w);                                       \
    _Pragma("unroll") for (int j = 0; j < 8; j++) acc[j] =       \
        fmaf(acc[j], scale, w * v[j]);                           \
    m = mn;                                                      \
  } while (0)

  int4 R0 = make_int4(0, 0, 0, 0), R1 = R0, R2 = R0, R3 = R0;
  if (deg > 0) {
    int dm1 = deg - 1;
    int s0 = csr[off];
    int s1 = csr[off + min(1, dm1)];
    int s2 = csr[off + min(2, dm1)];
    int s3 = csr[off + min(3, dm1)];
    R0 = *(const int4*)&ftb[s0 * F + dimBase];
    R1 = *(const int4*)&ftb[s1 * F + dimBase];
    R2 = *(const int4*)&ftb[s2 * F + dimBase];
    R3 = *(const int4*)&ftb[s3 * F + dimBase];
  }
  int i = 0;
  for (; i + 4 <= deg; i += 4) {
    int dm1 = deg - 1;
    int sa = csr[off + min(i + 4, dm1)];
    int sb = csr[off + min(i + 5, dm1)];
    int sc = csr[off + min(i + 6, dm1)];
    int sd = csr[off + min(i + 7, dm1)];
    int4 Na = *(const int4*)&ftb[sa * F + dimBase];
    int4 Nb = *(const int4*)&ftb[sb * F + dimBase];
    int4 Nc = *(const int4*)&ftb[sc * F + dimBase];
    int4 Nd = *(const int4*)&ftb[sd * F + dimBase];
    PROCESS(R0);
    PROCESS(R1);
    PROCESS(R2);
    PROCESS(R3);
    R0 = Na; R1 = Nb; R2 = Nc; R3 = Nd;
  }
  int r = deg - i;  // 0..3 remaining, already resident in R0..R2
  if (r > 0) PROCESS(R0);
  if (r > 1) PROCESS(R1);
  if (r > 2) PROCESS(R2);
#undef PROCESS

  float inv = (deg > 0) ? 1.f / s : 0.f;  // deg==0 -> out = bias
#pragma unroll
  for (int j = 0; j < 8; j++)
    out[n * F + dimBase + j] = acc[j] * inv + bias[dimBase + j];
}

// ---------------------------------------------------------------------------
extern "C" void kernel_launch(void* const* d_in, const int* in_sizes, int n_in,
                              void* d_out, int out_size, void* d_ws,
                              size_t ws_size, hipStream_t stream) {
  const float* feat = (const float*)d_in[0];
  const int* src = (const int*)d_in[1];
  const int* dst = (const int*)d_in[2];
  const float* W = (const float*)d_in[3];
  const float* bias = (const float*)d_in[4];
  float* out = (float*)d_out;

  const int N = in_sizes[0] / F;
  const int E = in_sizes[1];
  const int cw = (N + 7) >> 3;          // nodes per class (<= CW_MAX)
  const int cwp = (cw + 15) & ~15;      // padded row (64B aligned)

  // workspace layout (~70 MB used)
  char* ws = (char*)d_ws;
  ushort_t* ftb = (ushort_t*)ws;  // N*128 bf16 = 12.8 MB
  size_t ftB = (size_t)N * F * sizeof(ushort_t);
  ftB = (ftB + 255) & ~(size_t)255;
  int* counts = (int*)(ws + ftB);              // N
  int* offs = counts + N;                      // N
  int* bsums = offs + N;                       // 256
  int* csr = bsums + 256;                      // E
  ushort_t* whi = (ushort_t*)(csr + E);        // 16384 shorts (32 KB)
  ushort_t* wlo = whi + 128 * 128;             // 16384 shorts (32 KB)
  int* partials = (int*)(wlo + 128 * 128);     // 8*HIST_H*cwp ints (25.6 MB)
  int* cursors = partials + 8 * HIST_H * cwp;  // 8*HIST_H*cwp ints (25.6 MB)

  wprep_kernel<<<64, 256, 0, stream>>>(W, whi, wlo);

  gemm_kernel<<<(N + 63) / 64, 256, 0, stream>>>(feat, whi, wlo, ftb, N);

  hist_kernel<<<8 * HIST_H, 256, 0, stream>>>(dst, partials, cwp, E, N);

  int nb = (N + 255) / 256;  // 196 for N=50000 (must be <= 256)
  scan_block_kernel<<<nb, 256, 0, stream>>>(partials, cwp, counts, offs,
                                            bsums, N);
  scan_finish_kernel<<<nb, 256, 0, stream>>>(offs, bsums, partials, cursors,
                                             cwp, N);

  scatter_kernel<<<8 * HIST_H, 256, 0, stream>>>(src, dst, cursors, cwp, csr,
                                                 E, N);

  aggregate_kernel<<<(N * 16 + 255) / 256, 256, 0, stream>>>(
      ftb, offs, counts, csr, bias, out, N);
}

// Round 9
// 94.452 us; speedup vs baseline: 1.3779x; 1.1174x over previous
//
#include <hip/hip_runtime.h>
#include <math.h>

#define F 128
#define HEADS 4
#define DHEAD 32
#define HIST_H 128         // segments per class; 8*HIST_H hist/scatter blocks
#define CW_MAX 6592        // max nodes per class (LDS cap); N <= 52736

typedef unsigned short ushort_t;
typedef __attribute__((ext_vector_type(8))) short short8;   // 8 bf16 (4 VGPR)
typedef __attribute__((ext_vector_type(4))) float f32x4;    // MFMA acc

// round-to-nearest-even fp32 -> bf16
__device__ __forceinline__ ushort_t f2bf(float x) {
  unsigned u = __float_as_uint(x);
  unsigned r = u + 0x7FFFu + ((u >> 16) & 1u);
  return (ushort_t)(r >> 16);
}

// unpack 8 packed bf16 (as int4) -> 8 fp32
__device__ __forceinline__ void unpack8(const int4& r, float* v) {
  int rr[4] = {r.x, r.y, r.z, r.w};
#pragma unroll
  for (int q = 0; q < 4; q++) {
    unsigned u = (unsigned)rr[q];
    v[2 * q] = __uint_as_float(u << 16);
    v[2 * q + 1] = __uint_as_float(u & 0xFFFF0000u);
  }
}

// ---------------------------------------------------------------------------
// K-1: pack W (128x128 fp32) into MFMA-fragment-ordered bf16 hi/lo arrays.
// ---------------------------------------------------------------------------
__global__ __launch_bounds__(256) void wprep_kernel(
    const float* __restrict__ W, ushort_t* __restrict__ whi,
    ushort_t* __restrict__ wlo) {
  int idx = blockIdx.x * 256 + threadIdx.x;  // 0..16383
  if (idx >= 128 * 128) return;
  int j = idx & 7;
  int lane = (idx >> 3) & 63;
  int f = idx >> 9;  // kt*8+nt
  int kt = f >> 3, nt = f & 7;
  int k = kt * 32 + (lane >> 4) * 8 + j;
  int n = nt * 16 + (lane & 15);
  float w = W[k * 128 + n];
  unsigned u = __float_as_uint(w);
  unsigned hb = u & 0xFFFF0000u;
  float lo = w - __uint_as_float(hb);
  whi[idx] = (ushort_t)(hb >> 16);
  wlo[idx] = f2bf(lo);
}

// ---------------------------------------------------------------------------
// K1: fused  [0..gemmBlocks): ft = feat @ W via split-precision bf16 MFMA
//            [gemmBlocks..+8*HIST_H): LDS partial histograms -> u16 partials.
// Data-independent halves; hist's dst rescan hides behind GEMM's MFMA work.
// ---------------------------------------------------------------------------
__global__ __launch_bounds__(256) void gemm_hist_kernel(
    const float* __restrict__ feat, const ushort_t* __restrict__ whi,
    const ushort_t* __restrict__ wlo, ushort_t* __restrict__ ftb, int N,
    const int* __restrict__ dst, ushort_t* __restrict__ partials, int cwp,
    int E, int gemmBlocks) {
  __shared__ int lh[CW_MAX];
  if ((int)blockIdx.x >= gemmBlocks) {
    // ---- partial histogram path (LDS atomics only) ----
    const int hb = blockIdx.x - gemmBlocks;
    const int cls = hb & 7;
    const int h = hb >> 3;
    const int cw = (N + 7) >> 3;
    const int nbase = cls * cw;
    for (int j = threadIdx.x; j < cw; j += 256) lh[j] = 0;
    __syncthreads();
    const int seg = (E + HIST_H - 1) / HIST_H;
    const int e0 = h * seg;
    const int e1 = min(e0 + seg, E);
    int e = e0 + (int)threadIdx.x;
    for (; e + 768 < e1; e += 1024) {
      int d0 = dst[e];
      int d1 = dst[e + 256];
      int d2 = dst[e + 512];
      int d3 = dst[e + 768];
      if ((unsigned)(d0 - nbase) < (unsigned)cw) atomicAdd(&lh[d0 - nbase], 1);
      if ((unsigned)(d1 - nbase) < (unsigned)cw) atomicAdd(&lh[d1 - nbase], 1);
      if ((unsigned)(d2 - nbase) < (unsigned)cw) atomicAdd(&lh[d2 - nbase], 1);
      if ((unsigned)(d3 - nbase) < (unsigned)cw) atomicAdd(&lh[d3 - nbase], 1);
    }
    for (; e < e1; e += 256) {
      int d = dst[e];
      if ((unsigned)(d - nbase) < (unsigned)cw) atomicAdd(&lh[d - nbase], 1);
    }
    __syncthreads();
    ushort_t* prow = partials + (size_t)(cls * HIST_H + h) * cwp;
    for (int j = threadIdx.x; j < cw; j += 256) prow[j] = (ushort_t)lh[j];
    return;
  }
  // ---- MFMA GEMM path ----
  const int t = threadIdx.x;
  const int wv = t >> 6;  // wave 0..3
  const int l = t & 63;
  const int g = l >> 4;   // lane group 0..3
  const int lm = l & 15;
  const int arow = blockIdx.x * 64 + wv * 16 + lm;
  const int arowc = min(arow, N - 1);  // clamp OOB loads (rows independent)

  f32x4 acc[8];
#pragma unroll
  for (int nt = 0; nt < 8; nt++) acc[nt] = (f32x4){0.f, 0.f, 0.f, 0.f};

#pragma unroll
  for (int kt = 0; kt < 4; kt++) {
    const float* ap = feat + (size_t)arowc * F + kt * 32 + g * 8;
    float a[8];
    *(float4*)&a[0] = *(const float4*)ap;
    *(float4*)&a[4] = *(const float4*)(ap + 4);
    short8 ahi, alo;
#pragma unroll
    for (int j = 0; j < 8; j++) {
      unsigned u = __float_as_uint(a[j]);
      unsigned hb2 = u & 0xFFFF0000u;
      float lo = a[j] - __uint_as_float(hb2);
      ahi[j] = (short)(hb2 >> 16);
      alo[j] = (short)f2bf(lo);
    }
    const ushort_t* bh = whi + (size_t)(kt * 8) * 512 + l * 8;  // frag=512 sh
    const ushort_t* bl = wlo + (size_t)(kt * 8) * 512 + l * 8;
#pragma unroll
    for (int nt = 0; nt < 8; nt++) {
      short8 bhi = *(const short8*)(bh + nt * 512);
      short8 blo = *(const short8*)(bl + nt * 512);
      acc[nt] =
          __builtin_amdgcn_mfma_f32_16x16x32_bf16(ahi, blo, acc[nt], 0, 0, 0);
      acc[nt] =
          __builtin_amdgcn_mfma_f32_16x16x32_bf16(alo, bhi, acc[nt], 0, 0, 0);
      acc[nt] =
          __builtin_amdgcn_mfma_f32_16x16x32_bf16(ahi, bhi, acc[nt], 0, 0, 0);
    }
  }

  // epilogue: C/D layout col = lane&15, row = (lane>>4)*4 + reg (m89-verified)
  const int orow0 = blockIdx.x * 64 + wv * 16 + g * 4;
#pragma unroll
  for (int reg = 0; reg < 4; reg++) {
    int orow = orow0 + reg;
    if (orow < N) {
#pragma unroll
      for (int nt = 0; nt < 8; nt++)
        ftb[(size_t)orow * F + nt * 16 + lm] = f2bf(acc[nt][reg]);
    }
  }
}

// ---------------------------------------------------------------------------
// K3a: counts[n] = sum_h partials16[cls(n)][h][j(n)]; block-local exclusive
// prefix into offs + per-block sums.
// ---------------------------------------------------------------------------
__global__ void scan_block_kernel(const ushort_t* __restrict__ partials,
                                  int cwp, int* __restrict__ counts,
                                  int* __restrict__ offs,
                                  int* __restrict__ bsums, int N) {
  __shared__ int s[256];
  int t = threadIdx.x, i = blockIdx.x * 256 + t;
  int v = 0;
  if (i < N) {
    int cw = (N + 7) >> 3;
    int c = i / cw;
    int j = i - c * cw;
    const ushort_t* base = partials + (size_t)c * HIST_H * cwp + j;
#pragma unroll 8
    for (int h = 0; h < HIST_H; h++) v += base[(size_t)h * cwp];
    counts[i] = v;
  }
  s[t] = v;
  __syncthreads();
  for (int d = 1; d < 256; d <<= 1) {
    int x = (t >= d) ? s[t - d] : 0;
    __syncthreads();
    s[t] += x;
    __syncthreads();
  }
  if (i < N) offs[i] = s[t] - v;  // block-local exclusive
  if (t == 255) bsums[blockIdx.x] = s[255];
}

// K3b: finish offs with block-sum prefix; emit RELATIVE per-(class,segment)
// u16 cursors: rel16[c][h][j] = sum_{h'<h} partials[c][h'][j]  (<= deg <= u16)
__global__ void scan_finish_kernel(int* __restrict__ offs,
                                   const int* __restrict__ bsums,
                                   const ushort_t* __restrict__ partials,
                                   ushort_t* __restrict__ rel16, int cwp,
                                   int N) {
  int t = threadIdx.x, b = blockIdx.x;
  int v = (t < b) ? bsums[t] : 0;  // nb <= 256 guaranteed
#pragma unroll
  for (int d = 32; d > 0; d >>= 1) v += __shfl_down(v, d, 64);
  __shared__ int wsum[4];
  if ((t & 63) == 0) wsum[t >> 6] = v;
  __syncthreads();
  int total = wsum[0] + wsum[1] + wsum[2] + wsum[3];
  int i = b * 256 + t;
  if (i < N) {
    offs[i] += total;
    int cw = (N + 7) >> 3;
    int c = i / cw;
    int j = i - c * cw;
    const ushort_t* pb = partials + (size_t)c * HIST_H * cwp + j;
    ushort_t* cb = rel16 + (size_t)c * HIST_H * cwp + j;
    int run = 0;
#pragma unroll 8
    for (int h = 0; h < HIST_H; h++) {
      cb[(size_t)h * cwp] = (ushort_t)run;
      run += pb[(size_t)h * cwp];
    }
  }
}

// ---------------------------------------------------------------------------
// K4: scatter, zero global atomics. Block (cls,h): lcur[j] = offs[nbase+j]
// (L2-broadcast across the class's 128 same-XCD blocks) + rel16 row; rescans
// segment h (4-deep batched), LDS-atomicAdd -> exact csr slot. csr lines of
// a class owned by one XCD (bid&7) -> stores merge in L2.
// offs itself is NOT modified; it remains the start offset for aggregate.
// ---------------------------------------------------------------------------
__global__ __launch_bounds__(256) void scatter_kernel(
    const int* __restrict__ src, const int* __restrict__ dst,
    const int* __restrict__ offs, const ushort_t* __restrict__ rel16, int cwp,
    int* __restrict__ csr, int E, int N) {
  __shared__ int lcur[CW_MAX];
  const int cls = blockIdx.x & 7;
  const int h = blockIdx.x >> 3;
  const int cw = (N + 7) >> 3;
  const int nbase = cls * cw;
  const int jmax = min(cw, N - nbase);
  const ushort_t* crow = rel16 + (size_t)(cls * HIST_H + h) * cwp;
  for (int j = threadIdx.x; j < jmax; j += 256)
    lcur[j] = offs[nbase + j] + (int)crow[j];
  __syncthreads();
  const int seg = (E + HIST_H - 1) / HIST_H;
  const int e0 = h * seg;
  const int e1 = min(e0 + seg, E);
  int e = e0 + (int)threadIdx.x;
  for (; e + 768 < e1; e += 1024) {
    int d0 = dst[e];
    int d1 = dst[e + 256];
    int d2 = dst[e + 512];
    int d3 = dst[e + 768];
    int s0 = src[e];
    int s1 = src[e + 256];
    int s2 = src[e + 512];
    int s3 = src[e + 768];
    if ((unsigned)(d0 - nbase) < (unsigned)cw)
      csr[atomicAdd(&lcur[d0 - nbase], 1)] = s0;
    if ((unsigned)(d1 - nbase) < (unsigned)cw)
      csr[atomicAdd(&lcur[d1 - nbase], 1)] = s1;
    if ((unsigned)(d2 - nbase) < (unsigned)cw)
      csr[atomicAdd(&lcur[d2 - nbase], 1)] = s2;
    if ((unsigned)(d3 - nbase) < (unsigned)cw)
      csr[atomicAdd(&lcur[d3 - nbase], 1)] = s3;
  }
  for (; e < e1; e += 256) {
    int d = dst[e];
    int sv = src[e];
    if ((unsigned)(d - nbase) < (unsigned)cw)
      csr[atomicAdd(&lcur[d - nbase], 1)] = sv;
  }
}

// ---------------------------------------------------------------------------
// K5: fused per-node online-softmax aggregation, bf16 ft, 4-deep pipelined.
// ---------------------------------------------------------------------------
__global__ __launch_bounds__(256) void aggregate_kernel(
    const ushort_t* __restrict__ ftb, const int* __restrict__ offs,
    const int* __restrict__ counts, const int* __restrict__ csr,
    const float* __restrict__ bias, float* __restrict__ out, int N) {
  const int T = blockIdx.x * 256 + threadIdx.x;
  if (T >= N * 16) return;
  const int sub = T & 3;  // quarter of a head's D
  const int p = T >> 2;   // (node, head)
  const int h = p & 3;
  const int n = p >> 2;
  const int dimBase = h * DHEAD + sub * 8;

  const int deg = counts[n];
  const int off = offs[n];  // start offset (unmodified by scatter)

  float ftd[8];
  {
    int4 r = *(const int4*)&ftb[n * F + dimBase];
    unpack8(r, ftd);
  }

  const float LOG2E = 1.4426950408889634f;
  float m = -INFINITY, s = 0.f;
  float acc[8];
#pragma unroll
  for (int j = 0; j < 8; j++) acc[j] = 0.f;

#define PROCESS(RX)                                              \
  do {                                                           \
    float v[8];                                                  \
    unpack8(RX, v);                                              \
    float part = 0.f;                                            \
    _Pragma("unroll") for (int j = 0; j < 8; j++) part =         \
        fmaf(ftd[j], v[j], part);                                \
    part += __shfl_xor(part, 1, 4);                              \
    part += __shfl_xor(part, 2, 4);                              \
    float el = part * LOG2E;                                     \
    float mn = fmaxf(m, el);                                     \
    float scale = exp2f(m - mn);                                 \
    float w = exp2f(el - mn);                                    \
    s = fmaf(s, scale, w);                                       \
    _Pragma("unroll") for (int j = 0; j < 8; j++) acc[j] =       \
        fmaf(acc[j], scale, w * v[j]);                           \
    m = mn;                                                      \
  } while (0)

  int4 R0 = make_int4(0, 0, 0, 0), R1 = R0, R2 = R0, R3 = R0;
  if (deg > 0) {
    int dm1 = deg - 1;
    int s0 = csr[off];
    int s1 = csr[off + min(1, dm1)];
    int s2 = csr[off + min(2, dm1)];
    int s3 = csr[off + min(3, dm1)];
    R0 = *(const int4*)&ftb[s0 * F + dimBase];
    R1 = *(const int4*)&ftb[s1 * F + dimBase];
    R2 = *(const int4*)&ftb[s2 * F + dimBase];
    R3 = *(const int4*)&ftb[s3 * F + dimBase];
  }
  int i = 0;
  for (; i + 4 <= deg; i += 4) {
    int dm1 = deg - 1;
    int sa = csr[off + min(i + 4, dm1)];
    int sb = csr[off + min(i + 5, dm1)];
    int sc = csr[off + min(i + 6, dm1)];
    int sd = csr[off + min(i + 7, dm1)];
    int4 Na = *(const int4*)&ftb[sa * F + dimBase];
    int4 Nb = *(const int4*)&ftb[sb * F + dimBase];
    int4 Nc = *(const int4*)&ftb[sc * F + dimBase];
    int4 Nd = *(const int4*)&ftb[sd * F + dimBase];
    PROCESS(R0);
    PROCESS(R1);
    PROCESS(R2);
    PROCESS(R3);
    R0 = Na; R1 = Nb; R2 = Nc; R3 = Nd;
  }
  int r = deg - i;  // 0..3 remaining, already resident in R0..R2
  if (r > 0) PROCESS(R0);
  if (r > 1) PROCESS(R1);
  if (r > 2) PROCESS(R2);
#undef PROCESS

  float inv = (deg > 0) ? 1.f / s : 0.f;  // deg==0 -> out = bias
  float4 b0 = *(const float4*)&bias[dimBase];
  float4 b1 = *(const float4*)&bias[dimBase + 4];
  float4 o0 = make_float4(acc[0] * inv + b0.x, acc[1] * inv + b0.y,
                          acc[2] * inv + b0.z, acc[3] * inv + b0.w);
  float4 o1 = make_float4(acc[4] * inv + b1.x, acc[5] * inv + b1.y,
                          acc[6] * inv + b1.z, acc[7] * inv + b1.w);
  *(float4*)&out[n * F + dimBase] = o0;
  *(float4*)&out[n * F + dimBase + 4] = o1;
}

// ---------------------------------------------------------------------------
extern "C" void kernel_launch(void* const* d_in, const int* in_sizes, int n_in,
                              void* d_out, int out_size, void* d_ws,
                              size_t ws_size, hipStream_t stream) {
  const float* feat = (const float*)d_in[0];
  const int* src = (const int*)d_in[1];
  const int* dst = (const int*)d_in[2];
  const float* W = (const float*)d_in[3];
  const float* bias = (const float*)d_in[4];
  float* out = (float*)d_out;

  const int N = in_sizes[0] / F;
  const int E = in_sizes[1];
  const int cw = (N + 7) >> 3;          // nodes per class (<= CW_MAX)
  const int cwp = (cw + 31) & ~31;      // padded u16 row (64B aligned)

  // workspace layout (~45 MB used)
  char* ws = (char*)d_ws;
  ushort_t* ftb = (ushort_t*)ws;  // N*128 bf16 = 12.8 MB
  size_t ftB = (size_t)N * F * sizeof(ushort_t);
  ftB = (ftB + 255) & ~(size_t)255;
  int* counts = (int*)(ws + ftB);                 // N
  int* offs = counts + N;                         // N
  int* bsums = offs + N;                          // 256
  int* csr = bsums + 256;                         // E
  ushort_t* whi = (ushort_t*)(csr + E);           // 16384 shorts (32 KB)
  ushort_t* wlo = whi + 128 * 128;                // 16384 shorts (32 KB)
  ushort_t* partials = wlo + 128 * 128;           // 8*HIST_H*cwp u16 (12.9MB)
  ushort_t* rel16 = partials + 8 * HIST_H * cwp;  // 8*HIST_H*cwp u16 (12.9MB)

  wprep_kernel<<<64, 256, 0, stream>>>(W, whi, wlo);

  int gemmBlocks = (N + 63) / 64;
  gemm_hist_kernel<<<gemmBlocks + 8 * HIST_H, 256, 0, stream>>>(
      feat, whi, wlo, ftb, N, dst, partials, cwp, E, gemmBlocks);

  int nb = (N + 255) / 256;  // 196 for N=50000 (must be <= 256)
  scan_block_kernel<<<nb, 256, 0, stream>>>(partials, cwp, counts, offs,
                                            bsums, N);
  scan_finish_kernel<<<nb, 256, 0, stream>>>(offs, bsums, partials, rel16,
                                             cwp, N);

  scatter_kernel<<<8 * HIST_H, 256, 0, stream>>>(src, dst, offs, rel16, cwp,
                                                 csr, E, N);

  aggregate_kernel<<<(N * 16 + 255) / 256, 256, 0, stream>>>(
      ftb, offs, counts, csr, bias, out, N);
}